// Round 1
// baseline (310.053 us; speedup 1.0000x reference)
//
#include <hip/hip_runtime.h>
#include <math.h>

#define N 4096
#define F 256
#define NT 32            // N / BM tiles per dim
#define BM 128
#define BK 16
#define LDP (BM + 4)     // padded LDS row (132 words = 528B, keeps 16B alignment)

// ---------------- prep: Y = X*W (row-broadcast), sq[i] = ||Y_i||^2 ----------
__global__ __launch_bounds__(256)
void prep_kernel(const float* __restrict__ X1, const float* __restrict__ X2,
                 const float* __restrict__ W,
                 float* __restrict__ Y1, float* __restrict__ Y2,
                 float* __restrict__ sq1, float* __restrict__ sq2)
{
    int row = blockIdx.x & (N - 1);
    int b   = blockIdx.x >> 12;
    const float* X = b ? X2 : X1;
    float* Y  = b ? Y2 : Y1;
    float* sq = b ? sq2 : sq1;
    int t = threadIdx.x;          // 256 = F threads, one per feature
    float w = W[t];
    float y = X[(size_t)row * F + t] * w;
    Y[(size_t)row * F + t] = y;
    float s = y * y;
    #pragma unroll
    for (int off = 32; off > 0; off >>= 1) s += __shfl_down(s, off);
    __shared__ float red[4];
    int lane = t & 63, wv = t >> 6;
    if (lane == 0) red[wv] = s;
    __syncthreads();
    if (t == 0) sq[row] = red[0] + red[1] + red[2] + red[3];
}

// ---- fused tile kernel: G=Y Y^T tile -> temp/KL partials (upper triangle) --
__global__ __launch_bounds__(256)
void tsne_tile_kernel(const float* __restrict__ Y1, const float* __restrict__ Y2,
                      const float* __restrict__ sq1, const float* __restrict__ sq2,
                      const float* __restrict__ P1, const float* __restrict__ P2,
                      double* __restrict__ pS, double* __restrict__ pA,
                      double* __restrict__ pB)
{
    int bx = blockIdx.x, by = blockIdx.y, bz = blockIdx.z;
    int pidx = bz * (NT * NT) + by * NT + bx;
    if (bx < by) {  // lower-triangle tile: covered by mirror, write zero partials
        if (threadIdx.x == 0) { pS[pidx] = 0.0; pA[pidx] = 0.0; pB[pidx] = 0.0; }
        return;
    }
    const float* Y  = bz ? Y2 : Y1;
    const float* sq = bz ? sq2 : sq1;
    const float* P  = bz ? P2 : P1;
    const float wgt = (bx == by) ? 1.0f : 2.0f;

    __shared__ float As[BK][LDP];
    __shared__ float Bs[BK][LDP];

    const int t  = threadIdx.x;
    const int tx = t & 15, ty = t >> 4;

    float acc[8][8];
    #pragma unroll
    for (int m = 0; m < 8; ++m)
        #pragma unroll
        for (int n = 0; n < 8; ++n) acc[m][n] = 0.0f;

    const int arow = by * BM;
    const int brow = bx * BM;

    for (int k0 = 0; k0 < F; k0 += BK) {
        #pragma unroll
        for (int l = 0; l < 2; ++l) {
            int lf  = t + l * 256;       // float4 id 0..511 in the 128x16 tile
            int row = lf >> 2;
            int c4  = lf & 3;
            float4 av = *reinterpret_cast<const float4*>(
                &Y[(size_t)(arow + row) * F + k0 + c4 * 4]);
            As[c4 * 4 + 0][row] = av.x; As[c4 * 4 + 1][row] = av.y;
            As[c4 * 4 + 2][row] = av.z; As[c4 * 4 + 3][row] = av.w;
            float4 bv = *reinterpret_cast<const float4*>(
                &Y[(size_t)(brow + row) * F + k0 + c4 * 4]);
            Bs[c4 * 4 + 0][row] = bv.x; Bs[c4 * 4 + 1][row] = bv.y;
            Bs[c4 * 4 + 2][row] = bv.z; Bs[c4 * 4 + 3][row] = bv.w;
        }
        __syncthreads();
        #pragma unroll
        for (int kk = 0; kk < BK; ++kk) {
            float a[8], b[8];
            #pragma unroll
            for (int m = 0; m < 8; ++m) a[m] = As[kk][ty * 8 + m];
            #pragma unroll
            for (int n = 0; n < 8; ++n) b[n] = Bs[kk][tx * 8 + n];
            #pragma unroll
            for (int m = 0; m < 8; ++m)
                #pragma unroll
                for (int n = 0; n < 8; ++n) acc[m][n] += a[m] * b[n];
        }
        __syncthreads();
    }

    // ---------------- epilogue: temp, S/A/B partials ----------------
    const int gi0 = arow + ty * 8;
    const int gj0 = brow + tx * 8;
    float sqi[8], sqj[8];
    #pragma unroll
    for (int m = 0; m < 8; ++m) sqi[m] = sq[gi0 + m];
    #pragma unroll
    for (int n = 0; n < 8; ++n) sqj[n] = sq[gj0 + n];

    float sp = 0.0f, ap = 0.0f, bp = 0.0f;
    #pragma unroll
    for (int m = 0; m < 8; ++m) {
        const float4* prow = reinterpret_cast<const float4*>(
            &P[(size_t)(gi0 + m) * N + gj0]);
        float4 p0 = prow[0], p1 = prow[1];
        float pv[8] = {p0.x, p0.y, p0.z, p0.w, p1.x, p1.y, p1.z, p1.w};
        #pragma unroll
        for (int n = 0; n < 8; ++n) {
            float one_d2 = 1.0f + fmaxf(sqi[m] + sqj[n] - 2.0f * acc[m][n], 0.0f);
            bool diag = (gi0 + m) == (gj0 + n);
            if (!diag) {
                float p = pv[n];
                sp += __builtin_amdgcn_rcpf(one_d2);   // temp; ~1ulp, only feeds log(S)
                ap += p * logf(p * one_d2);            // P*log(P/temp)
                bp += p;
            }
        }
    }
    sp *= wgt; ap *= wgt; bp *= wgt;

    #pragma unroll
    for (int off = 32; off > 0; off >>= 1) {
        sp += __shfl_down(sp, off);
        ap += __shfl_down(ap, off);
        bp += __shfl_down(bp, off);
    }
    __shared__ float rS[4], rA[4], rB[4];
    int lane = t & 63, wv = t >> 6;
    if (lane == 0) { rS[wv] = sp; rA[wv] = ap; rB[wv] = bp; }
    __syncthreads();
    if (t == 0) {
        pS[pidx] = (double)(rS[0] + rS[1] + rS[2] + rS[3]);
        pA[pidx] = (double)(rA[0] + rA[1] + rA[2] + rA[3]);
        pB[pidx] = (double)(rB[0] + rB[1] + rB[2] + rB[3]);
    }
}

// ---------------- finish: kl_b = A_b + B_b * log(S_b); out = mean -----------
__global__ __launch_bounds__(256)
void finish_kernel(const double* __restrict__ pS, const double* __restrict__ pA,
                   const double* __restrict__ pB, float* __restrict__ out)
{
    int t = threadIdx.x;
    double s0 = 0, a0 = 0, b0 = 0, s1 = 0, a1 = 0, b1 = 0;
    for (int i = t; i < NT * NT; i += 256) {
        s0 += pS[i];           a0 += pA[i];           b0 += pB[i];
        s1 += pS[i + NT * NT]; a1 += pA[i + NT * NT]; b1 += pB[i + NT * NT];
    }
    __shared__ double red[6][256];
    red[0][t] = s0; red[1][t] = a0; red[2][t] = b0;
    red[3][t] = s1; red[4][t] = a1; red[5][t] = b1;
    __syncthreads();
    for (int off = 128; off > 0; off >>= 1) {
        if (t < off) {
            #pragma unroll
            for (int q = 0; q < 6; ++q) red[q][t] += red[q][t + off];
        }
        __syncthreads();
    }
    if (t == 0) {
        double kl1 = red[1][0] + red[2][0] * log(red[0][0]);
        double kl2 = red[4][0] + red[5][0] * log(red[3][0]);
        out[0] = (float)((kl1 + kl2) * 0.5);
    }
}

extern "C" void kernel_launch(void* const* d_in, const int* in_sizes, int n_in,
                              void* d_out, int out_size, void* d_ws, size_t ws_size,
                              hipStream_t stream)
{
    const float* P1 = (const float*)d_in[0];
    const float* P2 = (const float*)d_in[1];
    const float* X1 = (const float*)d_in[2];
    const float* X2 = (const float*)d_in[3];
    const float* W  = (const float*)d_in[4];
    float* out = (float*)d_out;

    float* Y1  = (float*)d_ws;
    float* Y2  = Y1 + (size_t)N * F;
    float* sq1 = Y2 + (size_t)N * F;
    float* sq2 = sq1 + N;
    double* pS = (double*)(sq2 + N);     // byte off (2*N*F+2*N)*4, 8-aligned
    double* pA = pS + 2 * NT * NT;
    double* pB = pA + 2 * NT * NT;

    prep_kernel<<<2 * N, 256, 0, stream>>>(X1, X2, W, Y1, Y2, sq1, sq2);
    tsne_tile_kernel<<<dim3(NT, NT, 2), 256, 0, stream>>>(Y1, Y2, sq1, sq2,
                                                          P1, P2, pS, pA, pB);
    finish_kernel<<<1, 256, 0, stream>>>(pS, pA, pB, out);
}

// Round 3
// 231.311 us; speedup vs baseline: 1.3404x; 1.3404x over previous
//
#include <hip/hip_runtime.h>
#include <math.h>

#define N 4096
#define F 256
#define NT 32            // N / BM
#define BM 128

typedef short short8 __attribute__((ext_vector_type(8)));
typedef float f32x4  __attribute__((ext_vector_type(4)));

typedef const __attribute__((address_space(1))) unsigned int guint_t;
typedef __attribute__((address_space(3))) unsigned int luint_t;

__device__ __forceinline__ void gload_lds16(const void* g, void* l) {
    // async global->LDS, 16B per lane; LDS dest = base + lane*16 (wave-linear)
    __builtin_amdgcn_global_load_lds((guint_t*)g, (luint_t*)l, 16, 0, 0);
}

__device__ __forceinline__ unsigned short f2bf(float x) {
    unsigned u = __float_as_uint(x);
    unsigned r = (u + 0x7fff + ((u >> 16) & 1)) >> 16;   // RNE
    return (unsigned short)r;
}
__device__ __forceinline__ float bf2f(unsigned short x) {
    return __uint_as_float(((unsigned)x) << 16);
}

// ------- prep: Y=X*W; split y = hi + lo (bf16 pair); sq = ||Y_i||^2 (fp32) --
__global__ __launch_bounds__(256)
void prep_kernel(const float* __restrict__ X1, const float* __restrict__ X2,
                 const float* __restrict__ W,
                 unsigned short* __restrict__ Yhi, unsigned short* __restrict__ Ylo,
                 float* __restrict__ sqg)
{
    int row = blockIdx.x & (N - 1);
    int b   = blockIdx.x >> 12;
    const float* X = b ? X2 : X1;
    size_t off = (size_t)b * N * F + (size_t)row * F;
    int t = threadIdx.x;                 // 256 == F
    float w = W[t];
    float y = X[(size_t)row * F + t] * w;
    unsigned short h = f2bf(y);
    float lf = y - bf2f(h);
    Yhi[off + t] = h;
    Ylo[off + t] = f2bf(lf);
    float s = y * y;
    #pragma unroll
    for (int o = 32; o > 0; o >>= 1) s += __shfl_down(s, o);
    __shared__ float red[4];
    int lane = t & 63, wv = t >> 6;
    if (lane == 0) red[wv] = s;
    __syncthreads();
    if (t == 0) sqg[b * N + row] = red[0] + red[1] + red[2] + red[3];
}

// ---- fused tile kernel: split-bf16 MFMA Gram tile -> KL partials ----------
__global__ __launch_bounds__(256)
void tsne_tile_kernel(const unsigned short* __restrict__ Yhi,
                      const unsigned short* __restrict__ Ylo,
                      const float* __restrict__ sqg,
                      const float* __restrict__ P1, const float* __restrict__ P2,
                      double* __restrict__ pS, double* __restrict__ pA,
                      double* __restrict__ pB)
{
    int bx = blockIdx.x, by = blockIdx.y, bz = blockIdx.z;
    int pidx = bz * (NT * NT) + by * NT + bx;
    if (bx < by) {
        if (threadIdx.x == 0) { pS[pidx] = 0.0; pA[pidx] = 0.0; pB[pidx] = 0.0; }
        return;
    }
    const float* P  = bz ? P2 : P1;
    const unsigned short* Ah = Yhi + (size_t)bz * N * F;
    const unsigned short* Al = Ylo + (size_t)bz * N * F;
    const float* sq = sqg + bz * N;
    const float wgt = (bx == by) ? 1.0f : 2.0f;

    __shared__ unsigned short sAh[BM * 32], sAl[BM * 32];
    __shared__ unsigned short sBh[BM * 32], sBl[BM * 32];

    const int t = threadIdx.x;
    const int lane = t & 63, w = t >> 6;
    const int wx = w & 1, wy = w >> 1;          // 2x2 waves, 64x64 tile each

    f32x4 acc[4][4];
    #pragma unroll
    for (int fm = 0; fm < 4; ++fm)
        #pragma unroll
        for (int fn = 0; fn < 4; ++fn) acc[fm][fn] = (f32x4){0.f, 0.f, 0.f, 0.f};

    const int arow = by * BM, brow = bx * BM;
    const int c = lane >> 4, mr = lane & 15;

    for (int k0 = 0; k0 < F; k0 += 32) {
        // ---- stage 128x32 hi/lo tiles for A and B panels (wave-linear LDS,
        //      XOR-swizzled GLOBAL chunk so reads can be bank-spread) ----
        #pragma unroll
        for (int it = 0; it < 2; ++it) {
            int cid = it * 256 + w * 64 + lane;      // 16B-chunk id 0..511
            int row = cid >> 2;                      // local row 0..127
            int kl  = cid & 3;                       // LDS chunk slot
            int kg  = kl ^ (row & 3);                // global k-chunk stored there
            int ldsoff = (it * 256 + w * 64) * 8;    // ushort units, wave-uniform
            size_t ga = (size_t)(arow + row) * F + k0 + kg * 8;
            size_t gb = (size_t)(brow + row) * F + k0 + kg * 8;
            gload_lds16(Ah + ga, &sAh[ldsoff]);
            gload_lds16(Al + ga, &sAl[ldsoff]);
            gload_lds16(Ah + gb, &sBh[ldsoff]);
            gload_lds16(Al + gb, &sBl[ldsoff]);
        }
        __syncthreads();

        short8 ah[4], al[4], bh[4], bl[4];
        #pragma unroll
        for (int fm = 0; fm < 4; ++fm) {
            int row = wy * 64 + fm * 16 + mr;
            int ad = row * 32 + ((c ^ (row & 3)) * 8);
            ah[fm] = *(const short8*)&sAh[ad];
            al[fm] = *(const short8*)&sAl[ad];
        }
        #pragma unroll
        for (int fn = 0; fn < 4; ++fn) {
            int row = wx * 64 + fn * 16 + mr;
            int ad = row * 32 + ((c ^ (row & 3)) * 8);
            bh[fn] = *(const short8*)&sBh[ad];
            bl[fn] = *(const short8*)&sBl[ad];
        }
        #pragma unroll
        for (int fm = 0; fm < 4; ++fm)
            #pragma unroll
            for (int fn = 0; fn < 4; ++fn) {
                acc[fm][fn] = __builtin_amdgcn_mfma_f32_16x16x32_bf16(ah[fm], bh[fn], acc[fm][fn], 0, 0, 0);
                acc[fm][fn] = __builtin_amdgcn_mfma_f32_16x16x32_bf16(ah[fm], bl[fn], acc[fm][fn], 0, 0, 0);
                acc[fm][fn] = __builtin_amdgcn_mfma_f32_16x16x32_bf16(al[fm], bh[fn], acc[fm][fn], 0, 0, 0);
            }
        __syncthreads();
    }

    // ---------------- epilogue ----------------
    const int q = lane >> 4, nn = lane & 15;
    const int gi0 = arow + wy * 64, gj0 = brow + wx * 64;
    float sp = 0.f, ap = 0.f, bp = 0.f;
    #pragma unroll
    for (int fm = 0; fm < 4; ++fm) {
        float sqi[4];
        #pragma unroll
        for (int r = 0; r < 4; ++r) sqi[r] = sq[gi0 + fm * 16 + q * 4 + r];
        #pragma unroll
        for (int fn = 0; fn < 4; ++fn) {
            int j = gj0 + fn * 16 + nn;
            float sqj = sq[j];
            #pragma unroll
            for (int r = 0; r < 4; ++r) {
                int i = gi0 + fm * 16 + q * 4 + r;
                float one_d2 = 1.0f + fmaxf(sqi[r] + sqj - 2.0f * acc[fm][fn][r], 0.0f);
                if (i != j) {
                    float p = P[(size_t)i * N + j];
                    sp += __builtin_amdgcn_rcpf(one_d2);   // temp (feeds log S only)
                    ap += p * logf(p * one_d2);            // P*log(P*(1+d2))
                    bp += p;
                }
            }
        }
    }
    sp *= wgt; ap *= wgt; bp *= wgt;

    #pragma unroll
    for (int o = 32; o > 0; o >>= 1) {
        sp += __shfl_down(sp, o);
        ap += __shfl_down(ap, o);
        bp += __shfl_down(bp, o);
    }
    __shared__ float rS[4], rA[4], rB[4];
    if (lane == 0) { rS[w] = sp; rA[w] = ap; rB[w] = bp; }
    __syncthreads();
    if (t == 0) {
        pS[pidx] = (double)(rS[0] + rS[1] + rS[2] + rS[3]);
        pA[pidx] = (double)(rA[0] + rA[1] + rA[2] + rA[3]);
        pB[pidx] = (double)(rB[0] + rB[1] + rB[2] + rB[3]);
    }
}

// ---------------- finish: kl_b = A_b + B_b * log(S_b); out = mean -----------
__global__ __launch_bounds__(256)
void finish_kernel(const double* __restrict__ pS, const double* __restrict__ pA,
                   const double* __restrict__ pB, float* __restrict__ out)
{
    int t = threadIdx.x;
    double s0 = 0, a0 = 0, b0 = 0, s1 = 0, a1 = 0, b1 = 0;
    for (int i = t; i < NT * NT; i += 256) {
        s0 += pS[i];           a0 += pA[i];           b0 += pB[i];
        s1 += pS[i + NT * NT]; a1 += pA[i + NT * NT]; b1 += pB[i + NT * NT];
    }
    __shared__ double red[6][256];
    red[0][t] = s0; red[1][t] = a0; red[2][t] = b0;
    red[3][t] = s1; red[4][t] = a1; red[5][t] = b1;
    __syncthreads();
    for (int o = 128; o > 0; o >>= 1) {
        if (t < o) {
            #pragma unroll
            for (int qd = 0; qd < 6; ++qd) red[qd][t] += red[qd][t + o];
        }
        __syncthreads();
    }
    if (t == 0) {
        double kl1 = red[1][0] + red[2][0] * log(red[0][0]);
        double kl2 = red[4][0] + red[5][0] * log(red[3][0]);
        out[0] = (float)((kl1 + kl2) * 0.5);
    }
}

extern "C" void kernel_launch(void* const* d_in, const int* in_sizes, int n_in,
                              void* d_out, int out_size, void* d_ws, size_t ws_size,
                              hipStream_t stream)
{
    const float* P1 = (const float*)d_in[0];
    const float* P2 = (const float*)d_in[1];
    const float* X1 = (const float*)d_in[2];
    const float* X2 = (const float*)d_in[3];
    const float* W  = (const float*)d_in[4];
    float* out = (float*)d_out;

    unsigned short* Yhi = (unsigned short*)d_ws;            // 2*N*F ushort
    unsigned short* Ylo = Yhi + (size_t)2 * N * F;          // 2*N*F ushort
    float* sq = (float*)(Ylo + (size_t)2 * N * F);          // 2*N floats
    double* pS = (double*)(sq + 2 * N);                     // 8-aligned
    double* pA = pS + 2 * NT * NT;
    double* pB = pA + 2 * NT * NT;

    prep_kernel<<<2 * N, 256, 0, stream>>>(X1, X2, W, Yhi, Ylo, sq);
    tsne_tile_kernel<<<dim3(NT, NT, 2), 256, 0, stream>>>(Yhi, Ylo, sq,
                                                          P1, P2, pS, pA, pB);
    finish_kernel<<<1, 256, 0, stream>>>(pS, pA, pB, out);
}

// Round 4
// 221.884 us; speedup vs baseline: 1.3974x; 1.0425x over previous
//
#include <hip/hip_runtime.h>
#include <math.h>

#define N 4096
#define F 256
#define NT 32            // N / BM
#define BM 128
#define BK 32

typedef short short8 __attribute__((ext_vector_type(8)));
typedef float f32x4  __attribute__((ext_vector_type(4)));

typedef const __attribute__((address_space(1))) unsigned int guint_t;
typedef __attribute__((address_space(3))) unsigned int luint_t;

__device__ __forceinline__ void gload_lds16(const void* g, void* l) {
    // async global->LDS, 16B per lane; LDS dest = wave-uniform base + lane*16
    __builtin_amdgcn_global_load_lds((guint_t*)g, (luint_t*)l, 16, 0, 0);
}

__device__ __forceinline__ unsigned short f2bf(float x) {
    unsigned u = __float_as_uint(x);
    unsigned r = (u + 0x7fff + ((u >> 16) & 1)) >> 16;   // RNE
    return (unsigned short)r;
}
__device__ __forceinline__ float bf2f(unsigned short x) {
    return __uint_as_float(((unsigned)x) << 16);
}

// ------- prep: Y=X*W; split y = hi + lo (bf16 pair); sq = ||Y_i||^2 --------
__global__ __launch_bounds__(256)
void prep_kernel(const float* __restrict__ X1, const float* __restrict__ X2,
                 const float* __restrict__ W,
                 unsigned short* __restrict__ Yhi, unsigned short* __restrict__ Ylo,
                 float* __restrict__ sqg)
{
    const int t = threadIdx.x;            // 256 == F
    const int rid0 = blockIdx.x * 8;      // 8 rows per block, rid in [0, 8192)
    const float w = W[t];
    __shared__ float red[8][4];
    const int lane = t & 63, wv = t >> 6;
    #pragma unroll
    for (int r = 0; r < 8; ++r) {
        int rid = rid0 + r;
        int b = rid >> 12, row = rid & (N - 1);
        const float* X = b ? X2 : X1;
        float y = X[(size_t)row * F + t] * w;
        unsigned short h = f2bf(y);
        float lf = y - bf2f(h);
        size_t off = (size_t)rid * F + t;
        Yhi[off] = h;
        Ylo[off] = f2bf(lf);
        float s = y * y;
        #pragma unroll
        for (int o = 32; o > 0; o >>= 1) s += __shfl_down(s, o);
        if (lane == 0) red[r][wv] = s;
    }
    __syncthreads();
    if (t < 8) {
        sqg[rid0 + t] = red[t][0] + red[t][1] + red[t][2] + red[t][3];
    }
}

// ---- fused tile kernel: split-bf16 MFMA Gram tile -> KL partials ----------
// Double-buffered LDS, prefetch-before-compute (T3-minimum schedule).
__global__ __launch_bounds__(256)
void tsne_tile_kernel(const unsigned short* __restrict__ Yhi,
                      const unsigned short* __restrict__ Ylo,
                      const float* __restrict__ sqg,
                      const float* __restrict__ P1, const float* __restrict__ P2,
                      double* __restrict__ pS, double* __restrict__ pA,
                      double* __restrict__ pB)
{
    int bx = blockIdx.x, by = blockIdx.y, bz = blockIdx.z;
    int pidx = bz * (NT * NT) + by * NT + bx;
    if (bx < by) {
        if (threadIdx.x == 0) { pS[pidx] = 0.0; pA[pidx] = 0.0; pB[pidx] = 0.0; }
        return;
    }
    const float* P  = bz ? P2 : P1;
    const unsigned short* Ah = Yhi + (size_t)bz * N * F;
    const unsigned short* Al = Ylo + (size_t)bz * N * F;
    const float* sq = sqg + bz * N;
    const float wgt = (bx == by) ? 1.0f : 2.0f;

    // [dbuf][Ah,Al,Bh,Bl][128*32] ushort = 65536 B exactly
    __shared__ unsigned short sbuf[2][4][BM * BK];

    const int t = threadIdx.x;
    const int lane = t & 63, w = t >> 6;
    const int wx = w & 1, wy = w >> 1;          // 2x2 waves, 64x64 tile each

    f32x4 acc[4][4];
    #pragma unroll
    for (int fm = 0; fm < 4; ++fm)
        #pragma unroll
        for (int fn = 0; fn < 4; ++fn) acc[fm][fn] = (f32x4){0.f, 0.f, 0.f, 0.f};

    const int arow = by * BM, brow = bx * BM;
    const int c = lane >> 4, mr = lane & 15;

    // stage one 128x32 hi/lo A+B tile set into buffer db.
    // chunk swizzle: slot kl at row holds global k-chunk kl ^ ((row>>1)&3)
    // -> uniform 8 lanes per 4-bank slot on the b128 read side (conflict-free)
#define STAGE(db, k0)                                                      \
    {                                                                      \
        _Pragma("unroll")                                                  \
        for (int it = 0; it < 2; ++it) {                                   \
            int cid = it * 256 + w * 64 + lane;                            \
            int row = cid >> 2;                                            \
            int kl  = cid & 3;                                             \
            int kg  = kl ^ ((row >> 1) & 3);                               \
            int ldsoff = (it * 256 + w * 64) * 8;                          \
            size_t ga = (size_t)(arow + row) * F + (k0) + kg * 8;          \
            size_t gb = (size_t)(brow + row) * F + (k0) + kg * 8;          \
            gload_lds16(Ah + ga, &sbuf[db][0][ldsoff]);                    \
            gload_lds16(Al + ga, &sbuf[db][1][ldsoff]);                    \
            gload_lds16(Ah + gb, &sbuf[db][2][ldsoff]);                    \
            gload_lds16(Al + gb, &sbuf[db][3][ldsoff]);                    \
        }                                                                  \
    }

    STAGE(0, 0);
    __syncthreads();

    for (int ks = 0; ks < F / BK; ++ks) {
        const int db = ks & 1;
        if (ks < F / BK - 1) STAGE(db ^ 1, (ks + 1) * BK);   // prefetch next

        short8 ah[4], al[4], bh[4], bl[4];
        #pragma unroll
        for (int fm = 0; fm < 4; ++fm) {
            int row = wy * 64 + fm * 16 + mr;
            int ad = row * BK + ((c ^ ((row >> 1) & 3)) * 8);
            ah[fm] = *(const short8*)&sbuf[db][0][ad];
            al[fm] = *(const short8*)&sbuf[db][1][ad];
        }
        #pragma unroll
        for (int fn = 0; fn < 4; ++fn) {
            int row = wx * 64 + fn * 16 + mr;
            int ad = row * BK + ((c ^ ((row >> 1) & 3)) * 8);
            bh[fn] = *(const short8*)&sbuf[db][2][ad];
            bl[fn] = *(const short8*)&sbuf[db][3][ad];
        }
        #pragma unroll
        for (int fm = 0; fm < 4; ++fm)
            #pragma unroll
            for (int fn = 0; fn < 4; ++fn) {
                acc[fm][fn] = __builtin_amdgcn_mfma_f32_16x16x32_bf16(ah[fm], bh[fn], acc[fm][fn], 0, 0, 0);
                acc[fm][fn] = __builtin_amdgcn_mfma_f32_16x16x32_bf16(ah[fm], bl[fn], acc[fm][fn], 0, 0, 0);
                acc[fm][fn] = __builtin_amdgcn_mfma_f32_16x16x32_bf16(al[fm], bh[fn], acc[fm][fn], 0, 0, 0);
            }
        __syncthreads();   // next buffer staged + this buffer free
    }
#undef STAGE

    // ---------------- epilogue ----------------
    const int q = lane >> 4, nn = lane & 15;
    const int gi0 = arow + wy * 64, gj0 = brow + wx * 64;
    float sp = 0.f, ap = 0.f, bp = 0.f;
    #pragma unroll
    for (int fm = 0; fm < 4; ++fm) {
        float sqi[4];
        #pragma unroll
        for (int r = 0; r < 4; ++r) sqi[r] = sq[gi0 + fm * 16 + q * 4 + r];
        #pragma unroll
        for (int fn = 0; fn < 4; ++fn) {
            int j = gj0 + fn * 16 + nn;
            float sqj = sq[j];
            #pragma unroll
            for (int r = 0; r < 4; ++r) {
                int i = gi0 + fm * 16 + q * 4 + r;
                float one_d2 = 1.0f + fmaxf(sqi[r] + sqj - 2.0f * acc[fm][fn][r], 0.0f);
                if (i != j) {
                    float p = P[(size_t)i * N + j];
                    sp += __builtin_amdgcn_rcpf(one_d2);   // temp (feeds log S only)
                    ap += p * __logf(p * one_d2);          // P*log(P*(1+d2))
                    bp += p;
                }
            }
        }
    }
    sp *= wgt; ap *= wgt; bp *= wgt;

    #pragma unroll
    for (int o = 32; o > 0; o >>= 1) {
        sp += __shfl_down(sp, o);
        ap += __shfl_down(ap, o);
        bp += __shfl_down(bp, o);
    }
    float* red = (float*)&sbuf[0][0][0];    // reuse LDS (k-loop fully done)
    if (lane == 0) { red[w] = sp; red[4 + w] = ap; red[8 + w] = bp; }
    __syncthreads();
    if (t == 0) {
        pS[pidx] = (double)(red[0] + red[1] + red[2] + red[3]);
        pA[pidx] = (double)(red[4] + red[5] + red[6] + red[7]);
        pB[pidx] = (double)(red[8] + red[9] + red[10] + red[11]);
    }
}

// ---------------- finish: kl_b = A_b + B_b * log(S_b); out = mean -----------
__global__ __launch_bounds__(256)
void finish_kernel(const double* __restrict__ pS, const double* __restrict__ pA,
                   const double* __restrict__ pB, float* __restrict__ out)
{
    int t = threadIdx.x;
    double s0 = 0, a0 = 0, b0 = 0, s1 = 0, a1 = 0, b1 = 0;
    for (int i = t; i < NT * NT; i += 256) {
        s0 += pS[i];           a0 += pA[i];           b0 += pB[i];
        s1 += pS[i + NT * NT]; a1 += pA[i + NT * NT]; b1 += pB[i + NT * NT];
    }
    __shared__ double red[6][256];
    red[0][t] = s0; red[1][t] = a0; red[2][t] = b0;
    red[3][t] = s1; red[4][t] = a1; red[5][t] = b1;
    __syncthreads();
    for (int o = 128; o > 0; o >>= 1) {
        if (t < o) {
            #pragma unroll
            for (int qd = 0; qd < 6; ++qd) red[qd][t] += red[qd][t + o];
        }
        __syncthreads();
    }
    if (t == 0) {
        double kl1 = red[1][0] + red[2][0] * log(red[0][0]);
        double kl2 = red[4][0] + red[5][0] * log(red[3][0]);
        out[0] = (float)((kl1 + kl2) * 0.5);
    }
}

extern "C" void kernel_launch(void* const* d_in, const int* in_sizes, int n_in,
                              void* d_out, int out_size, void* d_ws, size_t ws_size,
                              hipStream_t stream)
{
    const float* P1 = (const float*)d_in[0];
    const float* P2 = (const float*)d_in[1];
    const float* X1 = (const float*)d_in[2];
    const float* X2 = (const float*)d_in[3];
    const float* W  = (const float*)d_in[4];
    float* out = (float*)d_out;

    unsigned short* Yhi = (unsigned short*)d_ws;            // 2*N*F ushort
    unsigned short* Ylo = Yhi + (size_t)2 * N * F;          // 2*N*F ushort
    float* sq = (float*)(Ylo + (size_t)2 * N * F);          // 2*N floats
    double* pS = (double*)(sq + 2 * N);                     // 8-aligned
    double* pA = pS + 2 * NT * NT;
    double* pB = pA + 2 * NT * NT;

    prep_kernel<<<(2 * N) / 8, 256, 0, stream>>>(X1, X2, W, Yhi, Ylo, sq);
    tsne_tile_kernel<<<dim3(NT, NT, 2), 256, 0, stream>>>(Yhi, Ylo, sq,
                                                          P1, P2, pS, pA, pB);
    finish_kernel<<<1, 256, 0, stream>>>(pS, pA, pB, out);
}